// Round 4
// baseline (2208.264 us; speedup 1.0000x reference)
//
#include <hip/hip_runtime.h>
#include <math.h>

typedef unsigned short u16;
typedef __attribute__((ext_vector_type(8))) short bf8;    // 8 bf16 in 4 VGPRs
typedef __attribute__((ext_vector_type(4))) float f32x4;

constexpr int NB = 32;      // batch
constexpr int NP = 196;     // pixels
constexpr int NE = 2048;    // encoder dim
constexpr int ED = 512;     // embedding dim
constexpr int HH = 512;     // hidden
constexpr int AA = 512;     // attention dim
constexpr int NV = 10000;   // vocab
constexpr int NT = 20;      // timesteps

__device__ inline u16 f2bf(float f) {
    unsigned u = __builtin_bit_cast(unsigned, f);
    u += 0x7fffu + ((u >> 16) & 1u);          // RNE
    return (u16)(u >> 16);
}
__device__ inline float bf2f(u16 h) {
    return __builtin_bit_cast(float, (unsigned)h << 16);
}
__device__ inline void cvt4(const float* __restrict__ s, u16* __restrict__ d) {
    float4 v = *(const float4*)s;
    ushort4 o; o.x = f2bf(v.x); o.y = f2bf(v.y); o.z = f2bf(v.z); o.w = f2bf(v.w);
    *(ushort4*)d = o;
}

// async global->LDS, 16 bytes per lane (global_load_lds_dwordx4)
__device__ inline void gld16(const u16* g, u16* l) {
    __builtin_amdgcn_global_load_lds(
        (const __attribute__((address_space(1))) void*)g,
        (__attribute__((address_space(3))) void*)l, 16, 0, 0);
}

// ---------------------------------------------------------------------------
// one-shot: convert X + weights to bf16, build decW^T, gather embeddings,
// zero c/h/asum, init dpartf = dec_b (h0 = 0).
// ---------------------------------------------------------------------------
__global__ void k_convert(const float* __restrict__ enc, const float* __restrict__ enc_W,
                          const float* __restrict__ dec_W, const float* __restrict__ W_ih,
                          const float* __restrict__ W_hh, const float* __restrict__ fc_W,
                          const float* __restrict__ emb, const int* __restrict__ caps,
                          const float* __restrict__ dec_b,
                          u16* __restrict__ Xbf, u16* __restrict__ Wencbf,
                          u16* __restrict__ decWT, u16* __restrict__ Wihbf,
                          u16* __restrict__ Whhbf, u16* __restrict__ fcWbf,
                          u16* __restrict__ embg, float* __restrict__ cbuf,
                          u16* __restrict__ hbf, float* __restrict__ dpartf,
                          float* __restrict__ asum) {
    long g = (long)blockIdx.x * 256 + threadIdx.x;   // 4-element groups
    if (g < 3211264) { cvt4(enc + g * 4, Xbf + g * 4); return; }
    g -= 3211264;
    if (g < 262144) { cvt4(enc_W + g * 4, Wencbf + g * 4); return; }
    g -= 262144;
    if (g < 65536) {   // decWT[k][a] = dec_W[a][k]
        int a = (int)(g >> 7), k4 = (int)(g & 127) * 4;
        float4 v = *(const float4*)(dec_W + (size_t)a * 512 + k4);
        decWT[(size_t)(k4 + 0) * 512 + a] = f2bf(v.x);
        decWT[(size_t)(k4 + 1) * 512 + a] = f2bf(v.y);
        decWT[(size_t)(k4 + 2) * 512 + a] = f2bf(v.z);
        decWT[(size_t)(k4 + 3) * 512 + a] = f2bf(v.w);
        return;
    }
    g -= 65536;
    if (g < 1310720) { cvt4(W_ih + g * 4, Wihbf + g * 4); return; }
    g -= 1310720;
    if (g < 262144) { cvt4(W_hh + g * 4, Whhbf + g * 4); return; }
    g -= 262144;
    if (g < 1280000) { cvt4(fc_W + g * 4, fcWbf + g * 4); return; }
    g -= 1280000;
    if (g < 81920) {   // emb gather: embg[b][t][512]
        long e4 = (g & 127) * 4, w = g >> 7;
        long b = w / 20, t = w - b * 20;
        int tok = caps[b * 21 + t];
        cvt4(emb + (long)tok * 512 + e4, embg + w * 512 + e4);
        return;
    }
    g -= 81920;
    if (g < 4096) { *(float4*)(cbuf + g * 4) = make_float4(0.f, 0.f, 0.f, 0.f); return; }
    g -= 4096;
    if (g < 4096) { *(ushort4*)(hbf + g * 4) = make_ushort4(0, 0, 0, 0); return; }
    g -= 4096;
    if (g < 4096) {    // dpartf[b][j] = dec_b[j]  (h0 = 0)
        long idx = g * 4;
        *(float4*)(dpartf + idx) = *(const float4*)(dec_b + (idx & 511));
        return;
    }
    g -= 4096;
    if (g < 160) { *(float4*)(asum + g * 4) = make_float4(0.f, 0.f, 0.f, 0.f); return; }
}

// ---------------------------------------------------------------------------
// enc_proj = X(6272x2048) @ enc_W^T(2048x512) + enc_b, bf16 MFMA, f32 out.
// BM=64 x BN=128 tile, 4 waves x (32r x 64c), BK=32, double-buffered LDS,
// global_load_lds width-16 staging, K-split x2 (grid z). Grid (98,4,2)
// = 784 blocks = 3.06 blocks/CU (latency-overlap regime).
// kz=0 -> encproj (with bias); kz=1 -> scratch (= logits out buffer,
// 12.85 MB < 25.6 MB, overwritten by k_logits at the end).
// ---------------------------------------------------------------------------
__global__ __launch_bounds__(256) void k_encproj(const u16* __restrict__ Xbf,
                                                 const u16* __restrict__ Wencbf,
                                                 const float* __restrict__ enc_b,
                                                 float* __restrict__ encproj,
                                                 float* __restrict__ scratch) {
    __shared__ u16 As[2][64 * 32];    // 4 KB per buf
    __shared__ u16 Bs[2][128 * 32];   // 8 KB per buf
    int tid = threadIdx.x, lane = tid & 63, w = tid >> 6;
    int wr = w >> 1, wc = w & 1;                 // wave -> 32x64 sub-tile
    int i0 = blockIdx.x * 64, j0 = blockIdx.y * 128;
    int kbase = blockIdx.z * 1024;               // K-split 0..1
    int ar = lane & 15, kg = lane >> 4;          // fragment row / k-group

    // staging: 256 thr x 16 B; A tile 64x32 = 1 issue, B tile 128x32 = 2
    int srow = tid >> 2;                 // 0..63
    int sc = (tid & 3) * 8;              // u16 col within 32
    const u16* gA  = Xbf + (size_t)(i0 + srow) * NE + kbase + sc;
    const u16* gB0 = Wencbf + (size_t)(j0 + srow) * NE + kbase + sc;
    const u16* gB1 = Wencbf + (size_t)(j0 + 64 + srow) * NE + kbase + sc;

    f32x4 acc[2][4] = {};

#define STAGE_EP(buf, k0)                                   \
    do {                                                    \
        gld16(gA + (k0), &As[buf][tid * 8]);                \
        gld16(gB0 + (k0), &Bs[buf][tid * 8]);               \
        gld16(gB1 + (k0), &Bs[buf][2048 + tid * 8]);        \
    } while (0)

    STAGE_EP(0, 0);
    __syncthreads();
    for (int ks = 0; ks < 32; ++ks) {
        int cur = ks & 1;
        if (ks < 31) STAGE_EP(cur ^ 1, (ks + 1) * 32);
        bf8 a[2], b[4];
#pragma unroll
        for (int m = 0; m < 2; ++m)
            a[m] = *(const bf8*)(&As[cur][(wr * 32 + m * 16 + ar) * 32 + kg * 8]);
#pragma unroll
        for (int n = 0; n < 4; ++n)
            b[n] = *(const bf8*)(&Bs[cur][(wc * 64 + n * 16 + ar) * 32 + kg * 8]);
#pragma unroll
        for (int m = 0; m < 2; ++m)
#pragma unroll
            for (int n = 0; n < 4; ++n)
                acc[m][n] = __builtin_amdgcn_mfma_f32_16x16x32_bf16(a[m], b[n], acc[m][n], 0, 0, 0);
        if (ks < 31) __syncthreads();
    }
#undef STAGE_EP

    float* dst = (blockIdx.z == 0) ? encproj : scratch;
    int rbase = kg * 4;
#pragma unroll
    for (int m = 0; m < 2; ++m) {
        int row = i0 + wr * 32 + m * 16 + rbase;
#pragma unroll
        for (int n = 0; n < 4; ++n) {
            int col = j0 + wc * 64 + n * 16 + ar;
            float bias = (blockIdx.z == 0) ? enc_b[col] : 0.f;
#pragma unroll
            for (int r = 0; r < 4; ++r)
                dst[(size_t)(row + r) * AA + col] = acc[m][n][r] + bias;
        }
    }
}

// ---------------------------------------------------------------------------
// reduce the enc_proj K-partial: encproj += scratch  (3,211,264 f32)
// ---------------------------------------------------------------------------
__global__ __launch_bounds__(256) void k_epred(float* __restrict__ encproj,
                                               const float* __restrict__ scratch) {
    long i = ((long)blockIdx.x * 256 + threadIdx.x) * 4;
    f32x4 v = *(const f32x4*)(encproj + i);
    v += *(const f32x4*)(scratch + i);
    *(f32x4*)(encproj + i) = v;
}

// ---------------------------------------------------------------------------
// attexp[b,p] = exp(att_b + sum_a att_W[a]*tanh(enc_proj[b,p,a]+dpartf[b,a]))
// (no max-shift: |att| bounded ~3 so exp is safe; softmax is shift-invariant)
// lane0 atomically accumulates per-b denominator into asum[t*32+b].
// ---------------------------------------------------------------------------
__global__ __launch_bounds__(256) void k_attexp(const float* __restrict__ encproj,
                                                const float* __restrict__ dpartf,
                                                const float* __restrict__ att_W,
                                                const float* __restrict__ att_b,
                                                float* __restrict__ attb,
                                                float* __restrict__ asum, int t) {
    int tid = threadIdx.x, lane = tid & 63;
    int row = blockIdx.x * 4 + (tid >> 6);
    int b = row / NP;
    const f32x4* ep = (const f32x4*)(encproj + (size_t)row * AA);
    const f32x4* dp = (const f32x4*)(dpartf + (size_t)b * AA);
    const f32x4* aw = (const f32x4*)att_W;
    float s = 0.f;
#pragma unroll
    for (int h = 0; h < 2; ++h) {
        int ix = h * 64 + lane;
        f32x4 x = ep[ix];
        f32x4 d = dp[ix];
        f32x4 wv = aw[ix];
        s += tanhf(x[0] + d[0]) * wv[0] + tanhf(x[1] + d[1]) * wv[1] +
             tanhf(x[2] + d[2]) * wv[2] + tanhf(x[3] + d[3]) * wv[3];
    }
#pragma unroll
    for (int off = 32; off > 0; off >>= 1) s += __shfl_down(s, off, 64);
    if (lane == 0) {
        float e = expf(s + att_b[0]);
        attb[row] = e;
        unsafeAtomicAdd(&asum[t * 32 + b], e);
    }
}

// ---------------------------------------------------------------------------
// context from exp'd weights: ctx[b,:] = (sum_p attb[b,p]*X[b,p,:]) / asum
// grid (32 b x 16 chunks) x 512 thr; thread = (col, pgroup of 49), LDS reduce.
// ---------------------------------------------------------------------------
__global__ __launch_bounds__(512) void k_ctx(const float* __restrict__ attb,
                                             const float* __restrict__ asum,
                                             const u16* __restrict__ Xbf,
                                             u16* __restrict__ ctxbf, int t) {
    int b = blockIdx.x >> 4, chunk = blockIdx.x & 15;
    int tid = threadIdx.x;
    __shared__ float sa[NP];
    __shared__ float sred[4][128];
    if (tid < NP) sa[tid] = attb[b * NP + tid];
    __syncthreads();
    float inv = 1.f / asum[t * 32 + b];
    int col_l = tid & 127, pg = tid >> 7;
    int col = chunk * 128 + col_l;
    const u16* e = Xbf + (size_t)b * NP * NE + (size_t)pg * 49 * NE + col;
    float acc = 0.f;
#pragma unroll 7
    for (int p = 0; p < 49; ++p) acc += sa[pg * 49 + p] * bf2f(e[(size_t)p * NE]);
    sred[pg][col_l] = acc;
    __syncthreads();
    if (tid < 128) {
        float v = (sred[0][tid] + sred[1][tid] + sred[2][tid] + sred[3][tid]) * inv;
        ctxbf[b * NE + chunk * 128 + tid] = f2bf(v);
    }
}

// ---------------------------------------------------------------------------
// gates partials: [emb|ctx|h](32x3072) @ [W_ih;W_hh]^T -> gpart[8][32][2048]
// 256 blocks x 4 waves; wave = (ks 0..7, rg 0..1, cg 0..63): 16r x 32c, K 384
// ---------------------------------------------------------------------------
__global__ __launch_bounds__(256) void k_gates(const u16* __restrict__ embg,
                                               const u16* __restrict__ ctxbf,
                                               const u16* __restrict__ hbf,
                                               const u16* __restrict__ Wihbf,
                                               const u16* __restrict__ Whhbf,
                                               float* __restrict__ gpart, int t) {
    int tid = threadIdx.x, lane = tid & 63;
    int ww = blockIdx.x * 4 + (tid >> 6);      // 0..1023
    int cg = ww & 63, rg = (ww >> 6) & 1, ks = ww >> 7;
    int ar = lane & 15, koff = (lane >> 4) * 8;
    int arow = rg * 16 + ar;
    f32x4 acc[2] = {};
#pragma unroll
    for (int s = 0; s < 12; ++s) {
        int k0 = ks * 384 + s * 32;
        int k = k0 + koff;
        const u16* aptr;
        if (k0 < 512)        aptr = embg + ((size_t)arow * 20 + t) * 512 + k;
        else if (k0 < 2560)  aptr = ctxbf + (size_t)arow * NE + (k - 512);
        else                 aptr = hbf + (size_t)arow * HH + (k - 2560);
        bf8 a = *(const bf8*)aptr;
#pragma unroll
        for (int jt = 0; jt < 2; ++jt) {
            int c = cg * 32 + jt * 16 + ar;
            const u16* bptr = (k0 < 2560) ? (Wihbf + (size_t)c * 2560 + k)
                                          : (Whhbf + (size_t)c * 512 + (k - 2560));
            bf8 bfr = *(const bf8*)bptr;
            acc[jt] = __builtin_amdgcn_mfma_f32_16x16x32_bf16(a, bfr, acc[jt], 0, 0, 0);
        }
    }
    int bb = rg * 16 + (lane >> 4) * 4;
#pragma unroll
    for (int jt = 0; jt < 2; ++jt) {
        int col = cg * 32 + jt * 16 + ar;
#pragma unroll
        for (int r = 0; r < 4; ++r)
            gpart[(size_t)(ks * NB + bb + r) * 2048 + col] = acc[jt][r];
    }
}

// ---------------------------------------------------------------------------
// LSTM cell + fused dec_proj for step t+1.
// Block = one b (512 thr). Per thread j: sum 8 gate partials, activations,
// c update, h -> hbf/hallbf; then h (in LDS) @ dec_W^T via decWT (coalesced)
// -> dpartf[b][j] (includes dec_b).
// ---------------------------------------------------------------------------
__global__ __launch_bounds__(512) void k_cell(const float* __restrict__ gpart,
                                              const float* __restrict__ b_ih,
                                              const float* __restrict__ b_hh,
                                              const float* __restrict__ dec_b,
                                              const u16* __restrict__ decWT,
                                              float* __restrict__ cbuf,
                                              u16* __restrict__ hbf,
                                              u16* __restrict__ hallbf,
                                              float* __restrict__ dpartf, int t) {
    int b = blockIdx.x, j = threadIdx.x;
    __shared__ float sh[512];
    float g4[4];
#pragma unroll
    for (int q = 0; q < 4; ++q) {
        int col = j + q * 512;
        float s = b_ih[col] + b_hh[col];
#pragma unroll
        for (int ks = 0; ks < 8; ++ks) s += gpart[(size_t)(ks * NB + b) * 2048 + col];
        g4[q] = s;
    }
    float si = 1.f / (1.f + expf(-g4[0]));
    float sf = 1.f / (1.f + expf(-g4[1]));
    float so = 1.f / (1.f + expf(-g4[3]));
    float c2 = sf * cbuf[b * 512 + j] + si * tanhf(g4[2]);
    cbuf[b * 512 + j] = c2;
    float hv = so * tanhf(c2);
    u16 hb = f2bf(hv);
    hbf[b * 512 + j] = hb;
    hallbf[(b * 20 + t) * 512 + j] = hb;
    sh[j] = hv;
    __syncthreads();
    // dec_proj for next step: dpartf[b][j] = dec_b[j] + sum_k h[k]*decWT[k][j]
    float acc = 0.f;
#pragma unroll 8
    for (int k = 0; k < 512; ++k) acc += sh[k] * bf2f(decWT[(size_t)k * 512 + j]);
    dpartf[b * 512 + j] = acc + dec_b[j];
}

// ---------------------------------------------------------------------------
// logits (batched over all t): hall(640x512) @ fc_W^T(512x10000) + fc_b
// m97 structure: 128x128 tile, 4 waves x 64x64, BK=32, double-buffered LDS,
// global_load_lds width-16 staging. Grid (5, 79); B-rows clamped at NV,
// epilogue stores only col < NV.
// ---------------------------------------------------------------------------
__global__ __launch_bounds__(256) void k_logits(const u16* __restrict__ hallbf,
                                                const u16* __restrict__ fcWbf,
                                                const float* __restrict__ fc_b,
                                                float* __restrict__ out) {
    __shared__ u16 As[2][128 * 32];
    __shared__ u16 Bs[2][128 * 32];
    int tid = threadIdx.x, lane = tid & 63, w = tid >> 6;
    int wr = w >> 1, wc = w & 1;
    int i0 = blockIdx.x * 128, j0 = blockIdx.y * 128;
    int ar = lane & 15, kg = lane >> 4;

    int srow = tid >> 2;                 // 0..63
    int sc = (tid & 3) * 8;              // u16 col within 32
    int brow0 = min(j0 + srow, NV - 1);        // clamp: keep reads in-bounds
    int brow1 = min(j0 + 64 + srow, NV - 1);
    const u16* gA0 = hallbf + (size_t)(i0 + srow) * HH + sc;
    const u16* gA1 = hallbf + (size_t)(i0 + 64 + srow) * HH + sc;
    const u16* gB0 = fcWbf + (size_t)brow0 * HH + sc;
    const u16* gB1 = fcWbf + (size_t)brow1 * HH + sc;

    f32x4 acc[4][4] = {};

#define STAGE_LG(buf, k0)                                   \
    do {                                                    \
        gld16(gA0 + (k0), &As[buf][tid * 8]);               \
        gld16(gA1 + (k0), &As[buf][2048 + tid * 8]);        \
        gld16(gB0 + (k0), &Bs[buf][tid * 8]);               \
        gld16(gB1 + (k0), &Bs[buf][2048 + tid * 8]);        \
    } while (0)

    STAGE_LG(0, 0);
    __syncthreads();
    for (int ks = 0; ks < 16; ++ks) {
        int cur = ks & 1;
        if (ks < 15) STAGE_LG(cur ^ 1, (ks + 1) * 32);
        bf8 a[4], b[4];
#pragma unroll
        for (int m = 0; m < 4; ++m)
            a[m] = *(const bf8*)(&As[cur][(wr * 64 + m * 16 + ar) * 32 + kg * 8]);
#pragma unroll
        for (int n = 0; n < 4; ++n)
            b[n] = *(const bf8*)(&Bs[cur][(wc * 64 + n * 16 + ar) * 32 + kg * 8]);
#pragma unroll
        for (int m = 0; m < 4; ++m)
#pragma unroll
            for (int n = 0; n < 4; ++n)
                acc[m][n] = __builtin_amdgcn_mfma_f32_16x16x32_bf16(a[m], b[n], acc[m][n], 0, 0, 0);
        if (ks < 15) __syncthreads();
    }
#undef STAGE_LG

    int rbase = kg * 4;
#pragma unroll
    for (int m = 0; m < 4; ++m) {
        int row = i0 + wr * 64 + m * 16 + rbase;
#pragma unroll
        for (int n = 0; n < 4; ++n) {
            int col = j0 + wc * 64 + n * 16 + ar;
            if (col < NV) {
                float bias = fc_b[col];
#pragma unroll
                for (int r = 0; r < 4; ++r)
                    out[(size_t)(row + r) * NV + col] = acc[m][n][r] + bias;
            }
        }
    }
}

// ---------------------------------------------------------------------------
extern "C" void kernel_launch(void* const* d_in, const int* in_sizes, int n_in,
                              void* d_out, int out_size, void* d_ws, size_t ws_size,
                              hipStream_t stream) {
    (void)in_sizes; (void)n_in; (void)out_size; (void)ws_size;
    const float* enc   = (const float*)d_in[0];
    const int*   caps  = (const int*)d_in[1];
    const float* emb   = (const float*)d_in[2];
    const float* enc_W = (const float*)d_in[3];
    const float* enc_b = (const float*)d_in[4];
    const float* dec_W = (const float*)d_in[5];
    const float* dec_b = (const float*)d_in[6];
    const float* att_W = (const float*)d_in[7];
    const float* att_b = (const float*)d_in[8];
    const float* W_ih  = (const float*)d_in[9];
    const float* W_hh  = (const float*)d_in[10];
    const float* b_ih  = (const float*)d_in[11];
    const float* b_hh  = (const float*)d_in[12];
    const float* fc_W  = (const float*)d_in[13];
    const float* fc_b  = (const float*)d_in[14];
    float* out = (float*)d_out;

    char* base = (char*)d_ws;
    float* encproj = (float*)base;                 base += (size_t)6272 * 512 * 4;
    float* dpartf  = (float*)base;                 base += (size_t)32 * 512 * 4;
    float* attb    = (float*)base;                 base += (size_t)6272 * 4;
    float* cbuf    = (float*)base;                 base += (size_t)32 * 512 * 4;
    float* gpart   = (float*)base;                 base += (size_t)8 * 32 * 2048 * 4;
    float* asum    = (float*)base;                 base += (size_t)NT * 32 * 4;
    u16* Xbf    = (u16*)base;                      base += (size_t)32 * 196 * 2048 * 2;
    u16* Wencbf = (u16*)base;                      base += (size_t)512 * 2048 * 2;
    u16* decWT  = (u16*)base;                      base += (size_t)512 * 512 * 2;
    u16* Wihbf  = (u16*)base;                      base += (size_t)2048 * 2560 * 2;
    u16* Whhbf  = (u16*)base;                      base += (size_t)2048 * 512 * 2;
    u16* fcWbf  = (u16*)base;                      base += (size_t)10000 * 512 * 2;
    u16* embg   = (u16*)base;                      base += (size_t)32 * 20 * 512 * 2;
    u16* ctxbf  = (u16*)base;                      base += (size_t)32 * 2048 * 2;
    u16* hbf    = (u16*)base;                      base += (size_t)32 * 512 * 2;
    u16* hallbf = (u16*)base;                      base += (size_t)32 * 20 * 512 * 2;

    k_convert<<<25337, 256, 0, stream>>>(enc, enc_W, dec_W, W_ih, W_hh, fc_W, emb, caps,
                                         dec_b, Xbf, Wencbf, decWT, Wihbf, Whhbf, fcWbf,
                                         embg, cbuf, hbf, dpartf, asum);
    k_encproj<<<dim3(98, 4, 2), 256, 0, stream>>>(Xbf, Wencbf, enc_b, encproj, out);
    k_epred<<<3136, 256, 0, stream>>>(encproj, out);
    for (int t = 0; t < NT; ++t) {
        k_attexp<<<1568, 256, 0, stream>>>(encproj, dpartf, att_W, att_b, attb, asum, t);
        k_ctx<<<512, 512, 0, stream>>>(attb, asum, Xbf, ctxbf, t);
        k_gates<<<256, 256, 0, stream>>>(embg, ctxbf, hbf, Wihbf, Whhbf, gpart, t);
        k_cell<<<32, 512, 0, stream>>>(gpart, b_ih, b_hh, dec_b, decWT, cbuf, hbf,
                                       hallbf, dpartf, t);
    }
    k_logits<<<dim3(5, 79), 256, 0, stream>>>(hallbf, fcWbf, fc_b, out);
}

// Round 5
// 792.118 us; speedup vs baseline: 2.7878x; 2.7878x over previous
//
#include <hip/hip_runtime.h>
#include <math.h>

typedef unsigned short u16;
typedef __attribute__((ext_vector_type(8))) short bf8;    // 8 bf16 in 4 VGPRs
typedef __attribute__((ext_vector_type(4))) float f32x4;

constexpr int NB = 32;      // batch
constexpr int NP = 196;     // pixels
constexpr int NE = 2048;    // encoder dim
constexpr int ED = 512;     // embedding dim
constexpr int HH = 512;     // hidden
constexpr int AA = 512;     // attention dim
constexpr int NV = 10000;   // vocab
constexpr int NT = 20;      // timesteps

__device__ inline u16 f2bf(float f) {
    unsigned u = __builtin_bit_cast(unsigned, f);
    u += 0x7fffu + ((u >> 16) & 1u);          // RNE
    return (u16)(u >> 16);
}
__device__ inline float bf2f(u16 h) {
    return __builtin_bit_cast(float, (unsigned)h << 16);
}
__device__ inline void cvt4(const float* __restrict__ s, u16* __restrict__ d) {
    float4 v = *(const float4*)s;
    ushort4 o; o.x = f2bf(v.x); o.y = f2bf(v.y); o.z = f2bf(v.z); o.w = f2bf(v.w);
    *(ushort4*)d = o;
}

// async global->LDS, 16 bytes per lane (global_load_lds_dwordx4)
__device__ inline void gld16(const u16* g, u16* l) {
    __builtin_amdgcn_global_load_lds(
        (const __attribute__((address_space(1))) void*)g,
        (__attribute__((address_space(3))) void*)l, 16, 0, 0);
}

// ---------------------------------------------------------------------------
// one-shot: convert X + all weights to bf16, gather embeddings, zero c and h
// ---------------------------------------------------------------------------
__global__ void k_convert(const float* __restrict__ enc, const float* __restrict__ enc_W,
                          const float* __restrict__ dec_W, const float* __restrict__ W_ih,
                          const float* __restrict__ W_hh, const float* __restrict__ fc_W,
                          const float* __restrict__ emb, const int* __restrict__ caps,
                          u16* __restrict__ Xbf, u16* __restrict__ Wencbf,
                          u16* __restrict__ decWbf, u16* __restrict__ Wihbf,
                          u16* __restrict__ Whhbf, u16* __restrict__ fcWbf,
                          u16* __restrict__ embg, float* __restrict__ cbuf,
                          u16* __restrict__ hbf) {
    long g = (long)blockIdx.x * 256 + threadIdx.x;   // 4-element groups
    if (g < 3211264) { cvt4(enc + g * 4, Xbf + g * 4); return; }
    g -= 3211264;
    if (g < 262144) { cvt4(enc_W + g * 4, Wencbf + g * 4); return; }
    g -= 262144;
    if (g < 65536) { cvt4(dec_W + g * 4, decWbf + g * 4); return; }
    g -= 65536;
    if (g < 1310720) { cvt4(W_ih + g * 4, Wihbf + g * 4); return; }
    g -= 1310720;
    if (g < 262144) { cvt4(W_hh + g * 4, Whhbf + g * 4); return; }
    g -= 262144;
    if (g < 1280000) { cvt4(fc_W + g * 4, fcWbf + g * 4); return; }
    g -= 1280000;
    if (g < 81920) {   // emb gather: embg[b][t][512]
        long e4 = (g & 127) * 4, w = g >> 7;
        long b = w / 20, t = w - b * 20;
        int tok = caps[b * 21 + t];
        cvt4(emb + (long)tok * 512 + e4, embg + w * 512 + e4);
        return;
    }
    g -= 81920;
    if (g < 4096) { *(float4*)(cbuf + g * 4) = make_float4(0.f, 0.f, 0.f, 0.f); return; }
    g -= 4096;
    if (g < 4096) { *(ushort4*)(hbf + g * 4) = make_ushort4(0, 0, 0, 0); return; }
}

// ---------------------------------------------------------------------------
// enc_proj = X(6272x2048) @ enc_W^T(2048x512) + enc_b, bf16 MFMA, f32 out.
// BM=64 x BN=128 tile, 4 waves x (32r x 64c), BK=32, double-buffered LDS,
// global_load_lds width-16 staging, K-split x2 (grid z). Grid (98,4,2)
// = 784 blocks = 3.06 blocks/CU (latency-overlap regime).
// kz=0 -> encproj (with bias); kz=1 -> scratch (= logits out buffer,
// 12.85 MB < 25.6 MB, overwritten by k_logits at the end).
// ---------------------------------------------------------------------------
__global__ __launch_bounds__(256) void k_encproj(const u16* __restrict__ Xbf,
                                                 const u16* __restrict__ Wencbf,
                                                 const float* __restrict__ enc_b,
                                                 float* __restrict__ encproj,
                                                 float* __restrict__ scratch) {
    __shared__ u16 As[2][64 * 32];    // 4 KB per buf
    __shared__ u16 Bs[2][128 * 32];   // 8 KB per buf
    int tid = threadIdx.x, lane = tid & 63, w = tid >> 6;
    int wr = w >> 1, wc = w & 1;                 // wave -> 32x64 sub-tile
    int i0 = blockIdx.x * 64, j0 = blockIdx.y * 128;
    int kbase = blockIdx.z * 1024;               // K-split 0..1
    int ar = lane & 15, kg = lane >> 4;          // fragment row / k-group

    // staging: 256 thr x 16 B; A tile 64x32 = 1 issue, B tile 128x32 = 2
    int srow = tid >> 2;                 // 0..63
    int sc = (tid & 3) * 8;              // u16 col within 32
    const u16* gA  = Xbf + (size_t)(i0 + srow) * NE + kbase + sc;
    const u16* gB0 = Wencbf + (size_t)(j0 + srow) * NE + kbase + sc;
    const u16* gB1 = Wencbf + (size_t)(j0 + 64 + srow) * NE + kbase + sc;

    f32x4 acc[2][4] = {};

#define STAGE_EP(buf, k0)                                   \
    do {                                                    \
        gld16(gA + (k0), &As[buf][tid * 8]);                \
        gld16(gB0 + (k0), &Bs[buf][tid * 8]);               \
        gld16(gB1 + (k0), &Bs[buf][2048 + tid * 8]);        \
    } while (0)

    STAGE_EP(0, 0);
    __syncthreads();
    for (int ks = 0; ks < 32; ++ks) {
        int cur = ks & 1;
        if (ks < 31) STAGE_EP(cur ^ 1, (ks + 1) * 32);
        bf8 a[2], b[4];
#pragma unroll
        for (int m = 0; m < 2; ++m)
            a[m] = *(const bf8*)(&As[cur][(wr * 32 + m * 16 + ar) * 32 + kg * 8]);
#pragma unroll
        for (int n = 0; n < 4; ++n)
            b[n] = *(const bf8*)(&Bs[cur][(wc * 64 + n * 16 + ar) * 32 + kg * 8]);
#pragma unroll
        for (int m = 0; m < 2; ++m)
#pragma unroll
            for (int n = 0; n < 4; ++n)
                acc[m][n] = __builtin_amdgcn_mfma_f32_16x16x32_bf16(a[m], b[n], acc[m][n], 0, 0, 0);
        if (ks < 31) __syncthreads();
    }
#undef STAGE_EP

    float* dst = (blockIdx.z == 0) ? encproj : scratch;
    int rbase = kg * 4;
#pragma unroll
    for (int m = 0; m < 2; ++m) {
        int row = i0 + wr * 32 + m * 16 + rbase;
#pragma unroll
        for (int n = 0; n < 4; ++n) {
            int col = j0 + wc * 64 + n * 16 + ar;
            float bias = (blockIdx.z == 0) ? enc_b[col] : 0.f;
#pragma unroll
            for (int r = 0; r < 4; ++r)
                dst[(size_t)(row + r) * AA + col] = acc[m][n][r] + bias;
        }
    }
}

// ---------------------------------------------------------------------------
// reduce the enc_proj K-partial: encproj += scratch  (3,211,264 f32)
// ---------------------------------------------------------------------------
__global__ __launch_bounds__(256) void k_epred(float* __restrict__ encproj,
                                               const float* __restrict__ scratch) {
    long i = ((long)blockIdx.x * 256 + threadIdx.x) * 4;
    f32x4 v = *(const f32x4*)(encproj + i);
    v += *(const f32x4*)(scratch + i);
    *(f32x4*)(encproj + i) = v;
}

// ---------------------------------------------------------------------------
// dec_proj partials: h(32x512) @ dec_W^T -> dpart[4][32][512] (k-split 4)
// 16 blocks x 4 waves; wave = (ks, rg, cg): 16 rows x 64 cols, K-chunk 128
// ---------------------------------------------------------------------------
__global__ __launch_bounds__(256) void k_decproj(const u16* __restrict__ hbf,
                                                 const u16* __restrict__ decWbf,
                                                 float* __restrict__ dpart) {
    int tid = threadIdx.x, lane = tid & 63;
    int ww = blockIdx.x * 4 + (tid >> 6);
    int ks = ww >> 4, rem = ww & 15, rg = rem >> 3, cg = rem & 7;
    int ar = lane & 15, koff = (lane >> 4) * 8;
    const u16* Arow = hbf + (rg * 16 + ar) * HH + koff + ks * 128;
    f32x4 acc[4] = {};
#pragma unroll
    for (int s = 0; s < 4; ++s) {
        int k0 = s * 32;
        bf8 a = *(const bf8*)(Arow + k0);
#pragma unroll
        for (int jt = 0; jt < 4; ++jt) {
            bf8 b = *(const bf8*)(decWbf + (cg * 64 + jt * 16 + ar) * HH + ks * 128 + k0 + koff);
            acc[jt] = __builtin_amdgcn_mfma_f32_16x16x32_bf16(a, b, acc[jt], 0, 0, 0);
        }
    }
    int bb = rg * 16 + (lane >> 4) * 4;
#pragma unroll
    for (int jt = 0; jt < 4; ++jt) {
        int col = cg * 64 + jt * 16 + ar;
#pragma unroll
        for (int r = 0; r < 4; ++r)
            dpart[(ks * NB + bb + r) * AA + col] = acc[jt][r];
    }
}

// ---------------------------------------------------------------------------
// attexp[b,p] = exp(att_b + sum_a att_W[a]*tanh(enc_proj[b,p,a]+dec_proj[b,a]))
// No atomic (round-4 lesson: 196-deep same-address atomic chain = 67 us);
// softmax denominator is computed locally in k_ctx. No max-shift: |att|
// bounded (~3), softmax shift-invariant -> numerically safe, exact.
// ---------------------------------------------------------------------------
__global__ __launch_bounds__(256) void k_attexp(const float* __restrict__ encproj,
                                                const float* __restrict__ dpart,
                                                const float* __restrict__ dec_b,
                                                const float* __restrict__ att_W,
                                                const float* __restrict__ att_b,
                                                float* __restrict__ attb) {
    int tid = threadIdx.x, lane = tid & 63;
    int row = blockIdx.x * 4 + (tid >> 6);
    int b = row / NP;
    const f32x4* ep = (const f32x4*)(encproj + (size_t)row * AA);
    const f32x4* d0 = (const f32x4*)(dpart + b * AA);
    const f32x4* d1 = (const f32x4*)(dpart + (NB + b) * AA);
    const f32x4* d2 = (const f32x4*)(dpart + (2 * NB + b) * AA);
    const f32x4* d3 = (const f32x4*)(dpart + (3 * NB + b) * AA);
    const f32x4* db = (const f32x4*)dec_b;
    const f32x4* aw = (const f32x4*)att_W;
    float s = 0.f;
#pragma unroll
    for (int h = 0; h < 2; ++h) {
        int ix = h * 64 + lane;
        f32x4 x = ep[ix];
        f32x4 d = d0[ix] + d1[ix] + d2[ix] + d3[ix] + db[ix];
        f32x4 wv = aw[ix];
        s += tanhf(x[0] + d[0]) * wv[0] + tanhf(x[1] + d[1]) * wv[1] +
             tanhf(x[2] + d[2]) * wv[2] + tanhf(x[3] + d[3]) * wv[3];
    }
#pragma unroll
    for (int off = 32; off > 0; off >>= 1) s += __shfl_down(s, off, 64);
    if (lane == 0) attb[row] = expf(s + att_b[0]);
}

// ---------------------------------------------------------------------------
// context from exp'd weights: ctx[b,:] = (sum_p attb[b,p]*X[b,p,:]) / sum_p
// grid (32 b x 16 chunks) x 512 thr; local denominator reduce (no global
// communication), then thread = (col, pgroup of 49), LDS reduce.
// ---------------------------------------------------------------------------
__global__ __launch_bounds__(512) void k_ctx(const float* __restrict__ attb,
                                             const u16* __restrict__ Xbf,
                                             u16* __restrict__ ctxbf) {
    int b = blockIdx.x >> 4, chunk = blockIdx.x & 15;
    int tid = threadIdx.x;
    __shared__ float sa[NP];
    __shared__ float sred[4][128];
    __shared__ float ssum;
    if (tid < NP) sa[tid] = attb[b * NP + tid];
    __syncthreads();
    if (tid < 64) {
        float s = 0.f;
        for (int p = tid; p < NP; p += 64) s += sa[p];
#pragma unroll
        for (int off = 32; off > 0; off >>= 1) s += __shfl_down(s, off, 64);
        if (tid == 0) ssum = s;
    }
    __syncthreads();
    float inv = 1.f / ssum;
    int col_l = tid & 127, pg = tid >> 7;
    int col = chunk * 128 + col_l;
    const u16* e = Xbf + (size_t)b * NP * NE + (size_t)pg * 49 * NE + col;
    float acc = 0.f;
#pragma unroll 7
    for (int p = 0; p < 49; ++p) acc += sa[pg * 49 + p] * bf2f(e[(size_t)p * NE]);
    sred[pg][col_l] = acc;
    __syncthreads();
    if (tid < 128) {
        float v = (sred[0][tid] + sred[1][tid] + sred[2][tid] + sred[3][tid]) * inv;
        ctxbf[b * NE + chunk * 128 + tid] = f2bf(v);
    }
}

// ---------------------------------------------------------------------------
// gates partials: [emb|ctx|h](32x3072) @ [W_ih;W_hh]^T -> gpart[8][32][2048]
// 128 blocks x 4 waves; wave = (ks 0..7, rg 0..1, cg 0..31): 16r x 64c, K 384
// ---------------------------------------------------------------------------
__global__ __launch_bounds__(256) void k_gates(const u16* __restrict__ embg,
                                               const u16* __restrict__ ctxbf,
                                               const u16* __restrict__ hbf,
                                               const u16* __restrict__ Wihbf,
                                               const u16* __restrict__ Whhbf,
                                               float* __restrict__ gpart, int t) {
    int tid = threadIdx.x, lane = tid & 63;
    int ww = blockIdx.x * 4 + (tid >> 6);
    int cg = ww & 31, rg = (ww >> 5) & 1, ks = ww >> 6;
    int ar = lane & 15, koff = (lane >> 4) * 8;
    int arow = rg * 16 + ar;
    f32x4 acc[4] = {};
#pragma unroll
    for (int s = 0; s < 12; ++s) {
        int k0 = ks * 384 + s * 32;
        int k = k0 + koff;
        const u16* aptr;
        if (k0 < 512)        aptr = embg + ((size_t)arow * 20 + t) * 512 + k;
        else if (k0 < 2560)  aptr = ctxbf + (size_t)arow * NE + (k - 512);
        else                 aptr = hbf + (size_t)arow * HH + (k - 2560);
        bf8 a = *(const bf8*)aptr;
#pragma unroll
        for (int jt = 0; jt < 4; ++jt) {
            int c = cg * 64 + jt * 16 + ar;
            const u16* bptr = (k0 < 2560) ? (Wihbf + (size_t)c * 2560 + k)
                                          : (Whhbf + (size_t)c * 512 + (k - 2560));
            bf8 bfr = *(const bf8*)bptr;
            acc[jt] = __builtin_amdgcn_mfma_f32_16x16x32_bf16(a, bfr, acc[jt], 0, 0, 0);
        }
    }
    int bb = rg * 16 + (lane >> 4) * 4;
#pragma unroll
    for (int jt = 0; jt < 4; ++jt) {
        int col = cg * 64 + jt * 16 + ar;
#pragma unroll
        for (int r = 0; r < 4; ++r)
            gpart[(size_t)(ks * NB + bb + r) * 2048 + col] = acc[jt][r];
    }
}

// ---------------------------------------------------------------------------
// LSTM cell: sum 8 partials, biases, update c; h -> hbf (current) + hallbf[t]
// ---------------------------------------------------------------------------
__global__ void k_cell(const float* __restrict__ gpart, const float* __restrict__ b_ih,
                       const float* __restrict__ b_hh, float* __restrict__ cbuf,
                       u16* __restrict__ hbf, u16* __restrict__ hallbf, int t) {
    int idx = blockIdx.x * 256 + threadIdx.x;   // 16384
    int b = idx >> 9, j = idx & 511;
    float g4[4];
#pragma unroll
    for (int q = 0; q < 4; ++q) {
        int col = j + q * 512;
        float s = b_ih[col] + b_hh[col];
#pragma unroll
        for (int ks = 0; ks < 8; ++ks) s += gpart[(size_t)(ks * NB + b) * 2048 + col];
        g4[q] = s;
    }
    float si = 1.f / (1.f + expf(-g4[0]));
    float sf = 1.f / (1.f + expf(-g4[1]));
    float so = 1.f / (1.f + expf(-g4[3]));
    float c2 = sf * cbuf[idx] + si * tanhf(g4[2]);
    cbuf[idx] = c2;
    u16 hb = f2bf(so * tanhf(c2));
    hbf[b * 512 + j] = hb;
    hallbf[(b * 20 + t) * 512 + j] = hb;
}

// ---------------------------------------------------------------------------
// logits (batched over all t): hall(640x512) @ fc_W^T(512x10000) + fc_b
// m97 structure: 128x128 tile, 4 waves x 64x64, BK=32, double-buffered LDS,
// global_load_lds width-16 staging. Grid (5, 79); B-rows clamped at NV,
// epilogue stores only col < NV.
// ---------------------------------------------------------------------------
__global__ __launch_bounds__(256) void k_logits(const u16* __restrict__ hallbf,
                                                const u16* __restrict__ fcWbf,
                                                const float* __restrict__ fc_b,
                                                float* __restrict__ out) {
    __shared__ u16 As[2][128 * 32];
    __shared__ u16 Bs[2][128 * 32];
    int tid = threadIdx.x, lane = tid & 63, w = tid >> 6;
    int wr = w >> 1, wc = w & 1;
    int i0 = blockIdx.x * 128, j0 = blockIdx.y * 128;
    int ar = lane & 15, kg = lane >> 4;

    int srow = tid >> 2;                 // 0..63
    int sc = (tid & 3) * 8;              // u16 col within 32
    int brow0 = min(j0 + srow, NV - 1);        // clamp: keep reads in-bounds
    int brow1 = min(j0 + 64 + srow, NV - 1);
    const u16* gA0 = hallbf + (size_t)(i0 + srow) * HH + sc;
    const u16* gA1 = hallbf + (size_t)(i0 + 64 + srow) * HH + sc;
    const u16* gB0 = fcWbf + (size_t)brow0 * HH + sc;
    const u16* gB1 = fcWbf + (size_t)brow1 * HH + sc;

    f32x4 acc[4][4] = {};

#define STAGE_LG(buf, k0)                                   \
    do {                                                    \
        gld16(gA0 + (k0), &As[buf][tid * 8]);               \
        gld16(gA1 + (k0), &As[buf][2048 + tid * 8]);        \
        gld16(gB0 + (k0), &Bs[buf][tid * 8]);               \
        gld16(gB1 + (k0), &Bs[buf][2048 + tid * 8]);        \
    } while (0)

    STAGE_LG(0, 0);
    __syncthreads();
    for (int ks = 0; ks < 16; ++ks) {
        int cur = ks & 1;
        if (ks < 15) STAGE_LG(cur ^ 1, (ks + 1) * 32);
        bf8 a[4], b[4];
#pragma unroll
        for (int m = 0; m < 4; ++m)
            a[m] = *(const bf8*)(&As[cur][(wr * 64 + m * 16 + ar) * 32 + kg * 8]);
#pragma unroll
        for (int n = 0; n < 4; ++n)
            b[n] = *(const bf8*)(&Bs[cur][(wc * 64 + n * 16 + ar) * 32 + kg * 8]);
#pragma unroll
        for (int m = 0; m < 4; ++m)
#pragma unroll
            for (int n = 0; n < 4; ++n)
                acc[m][n] = __builtin_amdgcn_mfma_f32_16x16x32_bf16(a[m], b[n], acc[m][n], 0, 0, 0);
        if (ks < 15) __syncthreads();
    }
#undef STAGE_LG

    int rbase = kg * 4;
#pragma unroll
    for (int m = 0; m < 4; ++m) {
        int row = i0 + wr * 64 + m * 16 + rbase;
#pragma unroll
        for (int n = 0; n < 4; ++n) {
            int col = j0 + wc * 64 + n * 16 + ar;
            if (col < NV) {
                float bias = fc_b[col];
#pragma unroll
                for (int r = 0; r < 4; ++r)
                    out[(size_t)(row + r) * NV + col] = acc[m][n][r] + bias;
            }
        }
    }
}

// ---------------------------------------------------------------------------
extern "C" void kernel_launch(void* const* d_in, const int* in_sizes, int n_in,
                              void* d_out, int out_size, void* d_ws, size_t ws_size,
                              hipStream_t stream) {
    (void)in_sizes; (void)n_in; (void)out_size; (void)ws_size;
    const float* enc   = (const float*)d_in[0];
    const int*   caps  = (const int*)d_in[1];
    const float* emb   = (const float*)d_in[2];
    const float* enc_W = (const float*)d_in[3];
    const float* enc_b = (const float*)d_in[4];
    const float* dec_W = (const float*)d_in[5];
    const float* dec_b = (const float*)d_in[6];
    const float* att_W = (const float*)d_in[7];
    const float* att_b = (const float*)d_in[8];
    const float* W_ih  = (const float*)d_in[9];
    const float* W_hh  = (const float*)d_in[10];
    const float* b_ih  = (const float*)d_in[11];
    const float* b_hh  = (const float*)d_in[12];
    const float* fc_W  = (const float*)d_in[13];
    const float* fc_b  = (const float*)d_in[14];
    float* out = (float*)d_out;

    char* base = (char*)d_ws;
    float* encproj = (float*)base;                 base += (size_t)6272 * 512 * 4;
    float* dpart   = (float*)base;                 base += (size_t)4 * 32 * 512 * 4;
    float* attb    = (float*)base;                 base += (size_t)6272 * 4;
    float* cbuf    = (float*)base;                 base += (size_t)32 * 512 * 4;
    float* gpart   = (float*)base;                 base += (size_t)8 * 32 * 2048 * 4;
    u16* Xbf    = (u16*)base;                      base += (size_t)32 * 196 * 2048 * 2;
    u16* Wencbf = (u16*)base;                      base += (size_t)512 * 2048 * 2;
    u16* decWbf = (u16*)base;                      base += (size_t)512 * 512 * 2;
    u16* Wihbf  = (u16*)base;                      base += (size_t)2048 * 2560 * 2;
    u16* Whhbf  = (u16*)base;                      base += (size_t)2048 * 512 * 2;
    u16* fcWbf  = (u16*)base;                      base += (size_t)10000 * 512 * 2;
    u16* embg   = (u16*)base;                      base += (size_t)32 * 20 * 512 * 2;
    u16* ctxbf  = (u16*)base;                      base += (size_t)32 * 2048 * 2;
    u16* hbf    = (u16*)base;                      base += (size_t)32 * 512 * 2;
    u16* hallbf = (u16*)base;                      base += (size_t)32 * 20 * 512 * 2;

    k_convert<<<25320, 256, 0, stream>>>(enc, enc_W, dec_W, W_ih, W_hh, fc_W, emb, caps,
                                         Xbf, Wencbf, decWbf, Wihbf, Whhbf, fcWbf,
                                         embg, cbuf, hbf);
    k_encproj<<<dim3(98, 4, 2), 256, 0, stream>>>(Xbf, Wencbf, enc_b, encproj, out);
    k_epred<<<3136, 256, 0, stream>>>(encproj, out);
    for (int t = 0; t < NT; ++t) {
        k_decproj<<<16, 256, 0, stream>>>(hbf, decWbf, dpart);
        k_attexp<<<1568, 256, 0, stream>>>(encproj, dpart, dec_b, att_W, att_b, attb);
        k_ctx<<<512, 512, 0, stream>>>(attb, Xbf, ctxbf);
        k_gates<<<128, 256, 0, stream>>>(embg, ctxbf, hbf, Wihbf, Whhbf, gpart, t);
        k_cell<<<64, 256, 0, stream>>>(gpart, b_ih, b_hh, cbuf, hbf, hallbf, t);
    }
    k_logits<<<dim3(5, 79), 256, 0, stream>>>(hallbf, fcWbf, fc_b, out);
}